// Round 16
// baseline (662.864 us; speedup 1.0000x reference)
//
#include <hip/hip_runtime.h>
#include <hip/hip_bf16.h>
#include <math.h>

#define NB 16384
#define NH 16
#define ND 256
#define NM 1024
#define BM 128           // rows per block
#define MB 64            // m-chunk
#define NCH (NM / MB)    // 16

typedef float f32x4 __attribute__((ext_vector_type(4)));
typedef float f32x16 __attribute__((ext_vector_type(16)));
typedef short bf16x8 __attribute__((ext_vector_type(8)));
typedef unsigned short u16;
typedef unsigned int u32;

__device__ __forceinline__ u16 f2bf(float f) {
  union { float f; unsigned u; } v; v.f = f;
  unsigned r = v.u + 0x7FFFu + ((v.u >> 16) & 1u);
  return (u16)(r >> 16);
}

// UpF[h]: granule byte off = mc*32768 + kh*1024 + m*16, kh in [0,32), m in [0,64)
//   elems e: up[h][kh*8+e][mc*64+m]   (up fp32 [H][256][1024])
__global__ __launch_bounds__(256) void prep_up(const float* __restrict__ src,
                                               u16* __restrict__ dst) {
  __shared__ float tile[64][65];
  const int h = blockIdx.z;
  const int m0 = blockIdx.x * 64, d0 = blockIdx.y * 64;
  const int tr = threadIdx.x >> 6, tc = threadIdx.x & 63;
  const float* s = src + (size_t)h * ND * NM;
#pragma unroll
  for (int i = 0; i < 16; ++i) {
    int r = i * 4 + tr;
    tile[r][tc] = s[(size_t)(d0 + r) * NM + m0 + tc];
  }
  __syncthreads();
  char* dh = (char*)dst + (size_t)h * NM * ND * 2;
#pragma unroll
  for (int g = 0; g < 2; ++g) {
    int gi = g * 256 + threadIdx.x;
    int kh_l = gi >> 6, m_l = gi & 63;
    bf16x8 o;
#pragma unroll
    for (int e = 0; e < 8; ++e) o[e] = (short)f2bf(tile[kh_l * 8 + e][m_l]);
    *(bf16x8*)(dh + (size_t)(m0 >> 6) * 32768 + (size_t)((d0 >> 3) + kh_l) * 1024 + m_l * 16) = o;
  }
}

// DownF[h]: granule byte off = mc*32768 + kh*4096 + d*16, kh in [0,8), d in [0,256)
//   elems e: down[h][mc*64+kh*8+e][d]   (down fp32 [H][1024][256])
__global__ __launch_bounds__(256) void prep_down(const float* __restrict__ src,
                                                 u16* __restrict__ dst) {
  __shared__ float tile[64][65];
  const int h = blockIdx.z;
  const int mc = blockIdx.x, d0 = blockIdx.y * 64;
  const int tr = threadIdx.x >> 6, tc = threadIdx.x & 63;
  const float* s = src + (size_t)h * NM * ND;
#pragma unroll
  for (int i = 0; i < 16; ++i) {
    int r = i * 4 + tr;
    tile[r][tc] = s[(size_t)(mc * 64 + r) * ND + d0 + tc];
  }
  __syncthreads();
  char* dh = (char*)dst + (size_t)h * NM * ND * 2;
#pragma unroll
  for (int g = 0; g < 2; ++g) {
    int gi = g * 256 + threadIdx.x;
    int kh_l = gi >> 6, d_l = gi & 63;
    bf16x8 o;
#pragma unroll
    for (int e = 0; e < 8; ++e) o[e] = (short)f2bf(tile[kh_l * 8 + e][d_l]);
    *(bf16x8*)(dh + (size_t)mc * 32768 + (size_t)kh_l * 4096 + (size_t)(d0 + d_l) * 16) = o;
  }
}

// xp[b][i] = bf16(x[b][perm[i]])
__global__ __launch_bounds__(1024) void permute_x(const float* __restrict__ x,
                                                  const int* __restrict__ perm,
                                                  u16* __restrict__ xp) {
  const int b = blockIdx.x;
  const int t = threadIdx.x;
  const float* xr = x + (size_t)b * 4096;
  int4 p = *(const int4*)(perm + t * 4);
  ushort4 o;
  o.x = f2bf(xr[p.x]); o.y = f2bf(xr[p.y]);
  o.z = f2bf(xr[p.z]); o.w = f2bf(xr[p.w]);
  *(ushort4*)(xp + (size_t)b * 4096 + t * 4) = o;
}

// out[b][j] = fp32(pre[b][unperm[j]]); pre is the bf16 pre-unpermute output
// that mlp_fused wrote back into the xp buffer.
__global__ __launch_bounds__(1024) void unpermute_cvt(const u16* __restrict__ pre,
                                                      const int* __restrict__ unperm,
                                                      float* __restrict__ out) {
  __shared__ u16 row[4096];
  const int b = blockIdx.x;
  const int t = threadIdx.x;
  const u16* prow = pre + (size_t)b * 4096;
  *(ushort4*)(row + t * 4) = *(const ushort4*)(prow + t * 4);
  __syncthreads();
  int4 u = *(const int4*)(unperm + t * 4);
  f32x4 v;
  union { u32 u; float f; } c0, c1, c2, c3;
  c0.u = (u32)row[u.x] << 16; c1.u = (u32)row[u.y] << 16;
  c2.u = (u32)row[u.z] << 16; c3.u = (u32)row[u.w] << 16;
  v.x = c0.f; v.y = c1.f; v.z = c2.f; v.w = c3.f;
  *(f32x4*)(out + (size_t)b * 4096 + t * 4) = v;
}

// 16-wave PRODUCER/CONSUMER MLP, spill-free variant of R15 (376us, which
// still carried ~67MB scratch writes: one kernel allocates arch_max(A) +
// accum_max(B); A's xr[16]=64-arch + B's ca=64-accum = 148 > the hard 128
// cap at 16 co-resident waves).
// Fix: X lives in LDS (64KB, granule order [kh32][r128], staged ONCE in the
// prologue); Up streams from global (prep'd granule layout, 512B-coalesced,
// L2-resident) through a 4-deep register ring (16 transient VGPR). Us buffer
// and its staging/reads are GONE. A arch ~55 + accum 32 (2 pa chains);
// B unchanged (arch ~20, accum 64) -> 119 <= 128, no spill.
// LDS: X 64 + Ds 2x32 + Ps 2x16 = 160KB exactly.
// B-branch, GELU, Ps layout, epilogue (bf16 pre-out into xp), barrier
// structure: verbatim R15 (verified).
__global__ __launch_bounds__(1024, 4) void mlp_fused(
    u16* __restrict__ xp,
    const u16* __restrict__ upF,
    const u16* __restrict__ downF) {
  __shared__ __align__(16) u16 Xs[BM * ND];      // 64KB  [kh32][r128][8]
  __shared__ __align__(16) u16 Ds[2][ND * MB];   // 2x32KB [kh8][d256][8]
  __shared__ __align__(16) u16 Ps[2][BM * MB];   // 2x16KB [kh8][r128][8]

  const int h   = blockIdx.y;
  const int rb  = blockIdx.x;
  const int tid = threadIdx.x;
  const int w   = tid >> 6;
  const int l   = tid & 63;
  const int lo  = l & 31;
  const int hi  = l >> 5;
  const int row0 = rb * BM;

  const char* upH = (const char*)upF + (size_t)h * NM * ND * 2;
  const char* dnH = (const char*)downF + (size_t)h * NM * ND * 2;

  // ---- prologue: all 16 waves stage X[128r][256k] -> Xs granules (kh,r):
  //      granule t = kh*128 + r holds xp[row0+r][h*256 + kh*8 .. +7].
  //      LDS dest linear (t*16); global src per-lane (allowed).
  {
    const char* xpB = (const char*)xp + ((size_t)row0 * 4096 + (size_t)h * ND) * 2;
#pragma unroll
    for (int j = 0; j < 4; ++j) {
      int t = j * 1024 + tid;
      int r = t & 127, kh = t >> 7;
      const char* src = xpB + (size_t)r * 8192 + (size_t)kh * 16;
      __builtin_amdgcn_global_load_lds(
          (const __attribute__((address_space(1))) void*)src,
          (__attribute__((address_space(3))) void*)((char*)Xs + (size_t)t * 16),
          16, 0, 0);
    }
  }
  asm volatile("s_waitcnt vmcnt(0)" ::: "memory");
  __builtin_amdgcn_s_barrier();

  if (w < 8) {
    // ================= producer (A) =================
    const int rtA = w & 3;    // 32-row tile
    const int mt  = w >> 2;   // 32-m tile of the 64-m chunk

    // X read base (B-operand): lane l -> x-row rtA*32+lo, k = ks*16+hi*8+e
    //   byte = ks*4096 + hi*2048 + (rtA*32+lo)*16  (lane-linear)
    const char* const xb = (const char*)Xs + (size_t)hi * 2048 + (size_t)(rtA * 32 + lo) * 16;
    // Up global base (A-operand): granule kh*1024 + m*16, kh = ks*2+hi,
    //   m = mt*32+lo -> byte = ks*2048 + hi*1024 + (mt*32+lo)*16
    const char* const upW = upH + (size_t)hi * 1024 + (size_t)(mt * 32 + lo) * 16;
    char* const psW = (char*)&Ps[0][0] + (size_t)(rtA * 32 + lo) * 16 + hi * 8;

    for (int i = 0; i < NCH; ++i) {
      const int c = i & 1;
      const char* upC = upW + (size_t)i * 32768;

      // A(i): P^T[32m x 32r] = Up(global ring) @ X(LDS), 2 indep pa chains
      f32x16 pa0, pa1;
#pragma unroll
      for (int e = 0; e < 16; ++e) { pa0[e] = 0.f; pa1[e] = 0.f; }
      {
        bf16x8 a0 = *(const bf16x8*)(upC);
        bf16x8 a1 = *(const bf16x8*)(upC + 2048);
        bf16x8 a2 = *(const bf16x8*)(upC + 4096);
        bf16x8 a3 = *(const bf16x8*)(upC + 6144);
        __builtin_amdgcn_s_setprio(1);
#pragma unroll
        for (int ks = 0; ks < 16; ++ks) {
          bf16x8 cur = a0;
          a0 = a1; a1 = a2; a2 = a3;
          if (ks + 4 < 16)
            a3 = *(const bf16x8*)(upC + (size_t)(ks + 4) * 2048);
          bf16x8 xv = *(const bf16x8*)(xb + (size_t)ks * 4096);
          if (ks & 1) pa1 = __builtin_amdgcn_mfma_f32_32x32x16_bf16(cur, xv, pa1, 0, 0, 0);
          else        pa0 = __builtin_amdgcn_mfma_f32_32x32x16_bf16(cur, xv, pa0, 0, 0, 0);
        }
        __builtin_amdgcn_s_setprio(0);
      }
      f32x16 pa = pa0 + pa1;

      // gelu -> pack -> 4x ds_write_b64 into Ps[c]
      // pa[4g+e] = P[r=rtA*32+lo][m = mt*32 + g*8 + hi*4 + e]
#pragma unroll
      for (int g = 0; g < 4; ++g) {
        float gv[4];
#pragma unroll
        for (int e = 0; e < 4; ++e) {
          float v = pa[g * 4 + e];
          float p = __builtin_fmaf(0.1029433f, v * v, 2.3022082f);
          float ex = __builtin_amdgcn_exp2f(v * p);
          float r = __builtin_amdgcn_rcpf(ex + 1.0f);
          gv[e] = __builtin_fmaf(-v, r, v);
        }
        u32 w0, w1;
        asm("v_cvt_pk_bf16_f32 %0, %1, %2" : "=v"(w0) : "v"(gv[0]), "v"(gv[1]));
        asm("v_cvt_pk_bf16_f32 %0, %1, %2" : "=v"(w1) : "v"(gv[2]), "v"(gv[3]));
        uint2 pk; pk.x = w0; pk.y = w1;
        *(uint2*)(psW + (size_t)c * (BM * MB * 2) + (size_t)(mt * 4 + g) * 2048) = pk;
      }

      __builtin_amdgcn_sched_barrier(0);
      asm volatile("s_waitcnt lgkmcnt(0)" ::: "memory");   // Ps published
      __builtin_amdgcn_s_barrier();
      __builtin_amdgcn_sched_barrier(0);
    }
    // A-waves done (pre-out written by B-waves)
  } else {
    // ================= consumer (B) =================
    const int wb  = w - 8;
    const int rtp = wb & 1;   // 64-row half
    const int dq  = wb >> 1;  // 64-d quarter
    const int tb  = tid - 512;

    f32x16 ca[2][2];   // [rt2][dt] 32x32 tiles: 64r x 64d -> 64 VGPR
#pragma unroll
    for (int rt2 = 0; rt2 < 2; ++rt2)
#pragma unroll
      for (int dt = 0; dt < 2; ++dt)
#pragma unroll
        for (int e = 0; e < 16; ++e)
          ca[rt2][dt][e] = 0.f;

    for (int i = 0; i < NCH; ++i) {
      const int c = i & 1;
      // stage Ds(i) -> buf c (B-threads, 4 insts)
      {
        const char* src = dnH + (size_t)i * 32768;
#pragma unroll
        for (int j = 0; j < 4; ++j) {
          int t = j * 512 + tb;
          __builtin_amdgcn_global_load_lds(
              (const __attribute__((address_space(1))) void*)(src + (size_t)t * 16),
              (__attribute__((address_space(3))) void*)((char*)&Ds[c][0] + (size_t)t * 16),
              16, 0, 0);
        }
      }

      // B(i-1): C += Ps[c^1] @ Ds[c^1]
      if (i > 0) {
        const char* psb = (const char*)&Ps[c ^ 1][0];
        const char* dsb = (const char*)&Ds[c ^ 1][0];
        __builtin_amdgcn_s_setprio(1);
#pragma unroll
        for (int ks = 0; ks < 4; ++ks) {
          const size_t khp = (size_t)(ks * 2 + hi);
          bf16x8 a0 = *(const bf16x8*)(psb + khp * 2048 + (size_t)(rtp * 64 + lo) * 16);
          bf16x8 a1 = *(const bf16x8*)(psb + khp * 2048 + (size_t)(rtp * 64 + 32 + lo) * 16);
#pragma unroll
          for (int dt = 0; dt < 2; ++dt) {
            bf16x8 bv = *(const bf16x8*)(dsb + khp * 4096 + (size_t)(dq * 64 + dt * 32 + lo) * 16);
            ca[0][dt] = __builtin_amdgcn_mfma_f32_32x32x16_bf16(a0, bv, ca[0][dt], 0, 0, 0);
            ca[1][dt] = __builtin_amdgcn_mfma_f32_32x32x16_bf16(a1, bv, ca[1][dt], 0, 0, 0);
          }
        }
        __builtin_amdgcn_s_setprio(0);
      }

      __builtin_amdgcn_sched_barrier(0);
      asm volatile("s_waitcnt vmcnt(0)" ::: "memory");     // Ds(i) landed
      __builtin_amdgcn_s_barrier();
      __builtin_amdgcn_sched_barrier(0);
    }

    // final B(NCH-1): Ps[1], Ds[1]
    {
      const int c = (NCH - 1) & 1;
      const char* psb = (const char*)&Ps[c][0];
      const char* dsb = (const char*)&Ds[c][0];
      __builtin_amdgcn_s_setprio(1);
#pragma unroll
      for (int ks = 0; ks < 4; ++ks) {
        const size_t khp = (size_t)(ks * 2 + hi);
        bf16x8 a0 = *(const bf16x8*)(psb + khp * 2048 + (size_t)(rtp * 64 + lo) * 16);
        bf16x8 a1 = *(const bf16x8*)(psb + khp * 2048 + (size_t)(rtp * 64 + 32 + lo) * 16);
#pragma unroll
        for (int dt = 0; dt < 2; ++dt) {
          bf16x8 bv = *(const bf16x8*)(dsb + khp * 4096 + (size_t)(dq * 64 + dt * 32 + lo) * 16);
          ca[0][dt] = __builtin_amdgcn_mfma_f32_32x32x16_bf16(a0, bv, ca[0][dt], 0, 0, 0);
          ca[1][dt] = __builtin_amdgcn_mfma_f32_32x32x16_bf16(a1, bv, ca[1][dt], 0, 0, 0);
        }
      }
      __builtin_amdgcn_s_setprio(0);
    }

    // epilogue: bf16 pre-out into the xp buffer (coalesced u16 stores).
    // C-layout 32x32: col d = lo, row = (reg&3) + 8*(reg>>2) + 4*hi.
#pragma unroll
    for (int rt2 = 0; rt2 < 2; ++rt2)
#pragma unroll
      for (int dt = 0; dt < 2; ++dt) {
        const int d = h * ND + dq * 64 + dt * 32 + lo;
#pragma unroll
        for (int reg = 0; reg < 16; ++reg) {
          int r = rtp * 64 + rt2 * 32 + (reg & 3) + 8 * (reg >> 2) + 4 * hi;
          xp[(size_t)(row0 + r) * 4096 + d] = f2bf(ca[rt2][dt][reg]);
        }
      }
  }
}

extern "C" void kernel_launch(void* const* d_in, const int* in_sizes, int n_in,
                              void* d_out, int out_size, void* d_ws, size_t ws_size,
                              hipStream_t stream) {
  const float* x    = (const float*)d_in[0];
  const float* up   = (const float*)d_in[1];
  const float* down = (const float*)d_in[2];
  const int* perm   = (const int*)d_in[3];
  const int* unperm = (const int*)d_in[4];
  float* out = (float*)d_out;

  u16* upF   = (u16*)d_ws;                                   // 8 MB
  u16* downF = upF + (size_t)NH * NM * ND;                   // 8 MB
  u16* xp    = downF + (size_t)NH * NM * ND;                 // 128 MB (xp, then pre-out)

  // weights -> fragment-granule order (one-time, coalesced tile transposes)
  prep_up<<<dim3(NM / 64, ND / 64, NH), 256, 0, stream>>>(up, upF);
  prep_down<<<dim3(NM / 64, ND / 64, NH), 256, 0, stream>>>(down, downF);
  // xp[b][i] = bf16(x[b][perm[i]])
  permute_x<<<NB, 1024, 0, stream>>>(x, perm, xp);
  // main fused MLP: X-in-LDS, Up streamed from global, no spill. 160KB LDS.
  mlp_fused<<<dim3(NB / BM, NH), 1024, 0, stream>>>(xp, upF, downF);
  // unpermute + bf16->fp32 cvt into the real output
  unpermute_cvt<<<NB, 1024, 0, stream>>>(xp, unperm, out);
}

// Round 17
// 570.500 us; speedup vs baseline: 1.1619x; 1.1619x over previous
//
#include <hip/hip_runtime.h>
#include <hip/hip_bf16.h>
#include <math.h>

#define NB 16384
#define NH 16
#define ND 256
#define NM 1024
#define BM 128           // rows per block
#define MB 64            // m-chunk
#define NCH (NM / MB)    // 16

typedef float f32x4 __attribute__((ext_vector_type(4)));
typedef float f32x16 __attribute__((ext_vector_type(16)));
typedef short bf16x8 __attribute__((ext_vector_type(8)));
typedef unsigned short u16;
typedef unsigned int u32;

__device__ __forceinline__ u16 f2bf(float f) {
  union { float f; unsigned u; } v; v.f = f;
  unsigned r = v.u + 0x7FFFu + ((v.u >> 16) & 1u);
  return (u16)(r >> 16);
}

// UpF[h]: granule byte off = mc*32768 + kh*1024 + m*16, kh in [0,32), m in [0,64)
//   elems e: up[h][kh*8+e][mc*64+m]   (up fp32 [H][256][1024])
__global__ __launch_bounds__(256) void prep_up(const float* __restrict__ src,
                                               u16* __restrict__ dst) {
  __shared__ float tile[64][65];
  const int h = blockIdx.z;
  const int m0 = blockIdx.x * 64, d0 = blockIdx.y * 64;
  const int tr = threadIdx.x >> 6, tc = threadIdx.x & 63;
  const float* s = src + (size_t)h * ND * NM;
#pragma unroll
  for (int i = 0; i < 16; ++i) {
    int r = i * 4 + tr;
    tile[r][tc] = s[(size_t)(d0 + r) * NM + m0 + tc];
  }
  __syncthreads();
  char* dh = (char*)dst + (size_t)h * NM * ND * 2;
#pragma unroll
  for (int g = 0; g < 2; ++g) {
    int gi = g * 256 + threadIdx.x;
    int kh_l = gi >> 6, m_l = gi & 63;
    bf16x8 o;
#pragma unroll
    for (int e = 0; e < 8; ++e) o[e] = (short)f2bf(tile[kh_l * 8 + e][m_l]);
    *(bf16x8*)(dh + (size_t)(m0 >> 6) * 32768 + (size_t)((d0 >> 3) + kh_l) * 1024 + m_l * 16) = o;
  }
}

// DownF[h]: granule byte off = mc*32768 + kh*4096 + d*16, kh in [0,8), d in [0,256)
//   elems e: down[h][mc*64+kh*8+e][d]   (down fp32 [H][1024][256])
__global__ __launch_bounds__(256) void prep_down(const float* __restrict__ src,
                                                 u16* __restrict__ dst) {
  __shared__ float tile[64][65];
  const int h = blockIdx.z;
  const int mc = blockIdx.x, d0 = blockIdx.y * 64;
  const int tr = threadIdx.x >> 6, tc = threadIdx.x & 63;
  const float* s = src + (size_t)h * NM * ND;
#pragma unroll
  for (int i = 0; i < 16; ++i) {
    int r = i * 4 + tr;
    tile[r][tc] = s[(size_t)(mc * 64 + r) * ND + d0 + tc];
  }
  __syncthreads();
  char* dh = (char*)dst + (size_t)h * NM * ND * 2;
#pragma unroll
  for (int g = 0; g < 2; ++g) {
    int gi = g * 256 + threadIdx.x;
    int kh_l = gi >> 6, d_l = gi & 63;
    bf16x8 o;
#pragma unroll
    for (int e = 0; e < 8; ++e) o[e] = (short)f2bf(tile[kh_l * 8 + e][d_l]);
    *(bf16x8*)(dh + (size_t)mc * 32768 + (size_t)kh_l * 4096 + (size_t)(d0 + d_l) * 16) = o;
  }
}

// xp[b][i] = bf16(x[b][perm[i]])
__global__ __launch_bounds__(1024) void permute_x(const float* __restrict__ x,
                                                  const int* __restrict__ perm,
                                                  u16* __restrict__ xp) {
  const int b = blockIdx.x;
  const int t = threadIdx.x;
  const float* xr = x + (size_t)b * 4096;
  int4 p = *(const int4*)(perm + t * 4);
  ushort4 o;
  o.x = f2bf(xr[p.x]); o.y = f2bf(xr[p.y]);
  o.z = f2bf(xr[p.z]); o.w = f2bf(xr[p.w]);
  *(ushort4*)(xp + (size_t)b * 4096 + t * 4) = o;
}

// out[b][j] = fp32(pre[b][unperm[j]]); pre is the bf16 pre-unpermute output
// that mlp_fused wrote back into the xp buffer.
__global__ __launch_bounds__(1024) void unpermute_cvt(const u16* __restrict__ pre,
                                                      const int* __restrict__ unperm,
                                                      float* __restrict__ out) {
  __shared__ u16 row[4096];
  const int b = blockIdx.x;
  const int t = threadIdx.x;
  const u16* prow = pre + (size_t)b * 4096;
  *(ushort4*)(row + t * 4) = *(const ushort4*)(prow + t * 4);
  __syncthreads();
  int4 u = *(const int4*)(unperm + t * 4);
  f32x4 v;
  union { u32 u; float f; } c0, c1, c2, c3;
  c0.u = (u32)row[u.x] << 16; c1.u = (u32)row[u.y] << 16;
  c2.u = (u32)row[u.z] << 16; c3.u = (u32)row[u.w] << 16;
  v.x = c0.f; v.y = c1.f; v.z = c2.f; v.w = c3.f;
  *(f32x4*)(out + (size_t)b * 4096 + t * 4) = v;
}

// 12-wave (768-thread) PRODUCER/CONSUMER MLP. R15's structure verbatim, but
// 4 A-waves + 8 B-waves: 12 waves = 3 waves/SIMD -> 170-reg cap, so the
// role-split demand (arch_max(A: xr64+addr~80) + accum_max(B: ca 64) = 144)
// FITS with LDS weight staging intact. [R10-R15: 16 waves -> 128-reg cap ->
// every variant spilled ~70MB scratch; R16: spill-free via global Up streams
// but L2 latency in A's MFMA path cost +135us.]
//   A-waves (w<4, rtA=w): 32-row tile x BOTH 32-m tiles. Per chunk per mt:
//     16 Us reads + 16 MFMAs (2 indep chains) -> GELU -> 4x b64 Ps writes.
//   B-waves (w>=4): verbatim R15 (64r x 64d quarter, 16 reads / 16 MFMAs).
// Aggregate per-chunk pipe loads identical to R15 (256 MFMA, 256 LDS reads,
// 96KB staging); traded 4 waves of TLP for zero scratch.
// LDS: Us 2x32 + Ds 2x32 + Ps 2x16 = 160KB.
__global__ __launch_bounds__(768, 3) void mlp_fused(
    u16* __restrict__ xp,
    const u16* __restrict__ upF,
    const u16* __restrict__ downF) {
  __shared__ __align__(16) u16 Us[2][MB * ND];   // 2x32KB [kh32][m64][8]
  __shared__ __align__(16) u16 Ds[2][ND * MB];   // 2x32KB [kh8][d256][8]
  __shared__ __align__(16) u16 Ps[2][BM * MB];   // 2x16KB [kh8][r128][8]

  const int h   = blockIdx.y;
  const int rb  = blockIdx.x;
  const int tid = threadIdx.x;
  const int w   = tid >> 6;
  const int l   = tid & 63;
  const int lo  = l & 31;
  const int hi  = l >> 5;
  const int row0 = rb * BM;

  const char* upH = (const char*)upF + (size_t)h * NM * ND * 2;
  const char* dnH = (const char*)downF + (size_t)h * NM * ND * 2;

  // ---- prologue: A-threads (tid<256) stage Us(0), 8 insts each; barrier.
  if (tid < 256) {
#pragma unroll
    for (int j = 0; j < 8; ++j) {
      int t = j * 256 + tid;
      __builtin_amdgcn_global_load_lds(
          (const __attribute__((address_space(1))) void*)(upH + (size_t)t * 16),
          (__attribute__((address_space(3))) void*)((char*)&Us[0][0] + (size_t)t * 16),
          16, 0, 0);
    }
  }
  asm volatile("s_waitcnt vmcnt(0)" ::: "memory");
  __builtin_amdgcn_s_barrier();

  if (w < 4) {
    // ================= producer (A) =================
    const int rtA = w;        // 32-row tile (4 waves cover 128 rows)

    // X fragments: lane = x-row (rtA*32+lo), k = ks*16 + hi*8 + e. 64 VGPR.
    bf16x8 xr[16];
    {
      const char* px = (const char*)(xp + (size_t)(row0 + rtA * 32 + lo) * 4096 + h * ND);
#pragma unroll
      for (int ks = 0; ks < 16; ++ks)
        xr[ks] = *(const bf16x8*)(px + ks * 32 + hi * 16);
    }
    char* const psW = (char*)&Ps[0][0] + (size_t)(rtA * 32 + lo) * 16 + hi * 8;

    for (int i = 0; i < NCH; ++i) {
      const int c = i & 1;
      // stage Us(i+1) -> buf c^1 (A-threads: tid in [0,256), 8 insts)
      if (i + 1 < NCH) {
        const char* src = upH + (size_t)(i + 1) * 32768;
#pragma unroll
        for (int j = 0; j < 8; ++j) {
          int t = j * 256 + tid;
          __builtin_amdgcn_global_load_lds(
              (const __attribute__((address_space(1))) void*)(src + (size_t)t * 16),
              (__attribute__((address_space(3))) void*)((char*)&Us[c ^ 1][0] + (size_t)t * 16),
              16, 0, 0);
        }
      }

      // A(i): both 32-m tiles (mt=0,1); per mt: 16 MFMAs in 2 indep chains,
      // then GELU+pack immediately (keeps accum live-range small).
#pragma unroll
      for (int mt = 0; mt < 2; ++mt) {
        f32x16 pa0, pa1;
#pragma unroll
        for (int e = 0; e < 16; ++e) { pa0[e] = 0.f; pa1[e] = 0.f; }
        {
          const char* ub = (const char*)&Us[c][0] + (size_t)(mt * 32 + lo) * 16 + hi * 1024;
          __builtin_amdgcn_s_setprio(1);
#pragma unroll
          for (int ks = 0; ks < 16; ++ks) {
            bf16x8 av = *(const bf16x8*)(ub + (size_t)ks * 2048);
            if (ks & 1) pa1 = __builtin_amdgcn_mfma_f32_32x32x16_bf16(av, xr[ks], pa1, 0, 0, 0);
            else        pa0 = __builtin_amdgcn_mfma_f32_32x32x16_bf16(av, xr[ks], pa0, 0, 0, 0);
          }
          __builtin_amdgcn_s_setprio(0);
        }
        f32x16 pa = pa0 + pa1;

        // gelu -> pack -> 4x ds_write_b64 into Ps[c]
        // pa[4g+e] = P[r=rtA*32+lo][m = mt*32 + g*8 + hi*4 + e]
#pragma unroll
        for (int g = 0; g < 4; ++g) {
          float gv[4];
#pragma unroll
          for (int e = 0; e < 4; ++e) {
            float v = pa[g * 4 + e];
            float p = __builtin_fmaf(0.1029433f, v * v, 2.3022082f);
            float ex = __builtin_amdgcn_exp2f(v * p);
            float r = __builtin_amdgcn_rcpf(ex + 1.0f);
            gv[e] = __builtin_fmaf(-v, r, v);
          }
          u32 w0, w1;
          asm("v_cvt_pk_bf16_f32 %0, %1, %2" : "=v"(w0) : "v"(gv[0]), "v"(gv[1]));
          asm("v_cvt_pk_bf16_f32 %0, %1, %2" : "=v"(w1) : "v"(gv[2]), "v"(gv[3]));
          uint2 pk; pk.x = w0; pk.y = w1;
          *(uint2*)(psW + (size_t)c * (BM * MB * 2) + (size_t)(mt * 4 + g) * 2048) = pk;
        }
      }

      __builtin_amdgcn_sched_barrier(0);
      asm volatile("s_waitcnt lgkmcnt(0)" ::: "memory");   // Ps published
      asm volatile("s_waitcnt vmcnt(0)" ::: "memory");     // Us(i+1) landed
      __builtin_amdgcn_s_barrier();
      __builtin_amdgcn_sched_barrier(0);
    }
    // A-waves done (pre-out written by B-waves)
  } else {
    // ================= consumer (B) =================
    const int wb  = w - 4;
    const int rtp = wb & 1;   // 64-row half
    const int dq  = wb >> 1;  // 64-d quarter
    const int tb  = tid - 256;

    f32x16 ca[2][2];   // [rt2][dt] 32x32 tiles: 64r x 64d -> 64 VGPR
#pragma unroll
    for (int rt2 = 0; rt2 < 2; ++rt2)
#pragma unroll
      for (int dt = 0; dt < 2; ++dt)
#pragma unroll
        for (int e = 0; e < 16; ++e)
          ca[rt2][dt][e] = 0.f;

    for (int i = 0; i < NCH; ++i) {
      const int c = i & 1;
      // stage Ds(i) -> buf c (B-threads: tb in [0,512), 4 insts)
      {
        const char* src = dnH + (size_t)i * 32768;
#pragma unroll
        for (int j = 0; j < 4; ++j) {
          int t = j * 512 + tb;
          __builtin_amdgcn_global_load_lds(
              (const __attribute__((address_space(1))) void*)(src + (size_t)t * 16),
              (__attribute__((address_space(3))) void*)((char*)&Ds[c][0] + (size_t)t * 16),
              16, 0, 0);
        }
      }

      // B(i-1): C += Ps[c^1] @ Ds[c^1]
      if (i > 0) {
        const char* psb = (const char*)&Ps[c ^ 1][0];
        const char* dsb = (const char*)&Ds[c ^ 1][0];
        __builtin_amdgcn_s_setprio(1);
#pragma unroll
        for (int ks = 0; ks < 4; ++ks) {
          const size_t khp = (size_t)(ks * 2 + hi);
          bf16x8 a0 = *(const bf16x8*)(psb + khp * 2048 + (size_t)(rtp * 64 + lo) * 16);
          bf16x8 a1 = *(const bf16x8*)(psb + khp * 2048 + (size_t)(rtp * 64 + 32 + lo) * 16);
#pragma unroll
          for (int dt = 0; dt < 2; ++dt) {
            bf16x8 bv = *(const bf16x8*)(dsb + khp * 4096 + (size_t)(dq * 64 + dt * 32 + lo) * 16);
            ca[0][dt] = __builtin_amdgcn_mfma_f32_32x32x16_bf16(a0, bv, ca[0][dt], 0, 0, 0);
            ca[1][dt] = __builtin_amdgcn_mfma_f32_32x32x16_bf16(a1, bv, ca[1][dt], 0, 0, 0);
          }
        }
        __builtin_amdgcn_s_setprio(0);
      }

      __builtin_amdgcn_sched_barrier(0);
      asm volatile("s_waitcnt vmcnt(0)" ::: "memory");     // Ds(i) landed
      __builtin_amdgcn_s_barrier();
      __builtin_amdgcn_sched_barrier(0);
    }

    // final B(NCH-1): Ps[1], Ds[1]
    {
      const int c = (NCH - 1) & 1;
      const char* psb = (const char*)&Ps[c][0];
      const char* dsb = (const char*)&Ds[c][0];
      __builtin_amdgcn_s_setprio(1);
#pragma unroll
      for (int ks = 0; ks < 4; ++ks) {
        const size_t khp = (size_t)(ks * 2 + hi);
        bf16x8 a0 = *(const bf16x8*)(psb + khp * 2048 + (size_t)(rtp * 64 + lo) * 16);
        bf16x8 a1 = *(const bf16x8*)(psb + khp * 2048 + (size_t)(rtp * 64 + 32 + lo) * 16);
#pragma unroll
        for (int dt = 0; dt < 2; ++dt) {
          bf16x8 bv = *(const bf16x8*)(dsb + khp * 4096 + (size_t)(dq * 64 + dt * 32 + lo) * 16);
          ca[0][dt] = __builtin_amdgcn_mfma_f32_32x32x16_bf16(a0, bv, ca[0][dt], 0, 0, 0);
          ca[1][dt] = __builtin_amdgcn_mfma_f32_32x32x16_bf16(a1, bv, ca[1][dt], 0, 0, 0);
        }
      }
      __builtin_amdgcn_s_setprio(0);
    }

    // epilogue: bf16 pre-out into the xp buffer (coalesced u16 stores).
    // C-layout 32x32: col d = lo, row = (reg&3) + 8*(reg>>2) + 4*hi.
#pragma unroll
    for (int rt2 = 0; rt2 < 2; ++rt2)
#pragma unroll
      for (int dt = 0; dt < 2; ++dt) {
        const int d = h * ND + dq * 64 + dt * 32 + lo;
#pragma unroll
        for (int reg = 0; reg < 16; ++reg) {
          int r = rtp * 64 + rt2 * 32 + (reg & 3) + 8 * (reg >> 2) + 4 * hi;
          xp[(size_t)(row0 + r) * 4096 + d] = f2bf(ca[rt2][dt][reg]);
        }
      }
  }
}

extern "C" void kernel_launch(void* const* d_in, const int* in_sizes, int n_in,
                              void* d_out, int out_size, void* d_ws, size_t ws_size,
                              hipStream_t stream) {
  const float* x    = (const float*)d_in[0];
  const float* up   = (const float*)d_in[1];
  const float* down = (const float*)d_in[2];
  const int* perm   = (const int*)d_in[3];
  const int* unperm = (const int*)d_in[4];
  float* out = (float*)d_out;

  u16* upF   = (u16*)d_ws;                                   // 8 MB
  u16* downF = upF + (size_t)NH * NM * ND;                   // 8 MB
  u16* xp    = downF + (size_t)NH * NM * ND;                 // 128 MB (xp, then pre-out)

  // weights -> fragment-granule order (one-time, coalesced tile transposes)
  prep_up<<<dim3(NM / 64, ND / 64, NH), 256, 0, stream>>>(up, upF);
  prep_down<<<dim3(NM / 64, ND / 64, NH), 256, 0, stream>>>(down, downF);
  // xp[b][i] = bf16(x[b][perm[i]])
  permute_x<<<NB, 1024, 0, stream>>>(x, perm, xp);
  // main fused MLP: 768 thr (4 producer + 8 consumer waves), 160KB LDS,
  // 170-reg cap -> no spill with LDS staging intact.
  mlp_fused<<<dim3(NB / BM, NH), 768, 0, stream>>>(xp, upF, downF);
  // unpermute + bf16->fp32 cvt into the real output
  unpermute_cvt<<<NB, 1024, 0, stream>>>(xp, unperm, out);
}

// Round 18
// 538.580 us; speedup vs baseline: 1.2308x; 1.0593x over previous
//
#include <hip/hip_runtime.h>
#include <hip/hip_bf16.h>
#include <math.h>

#define NB 16384
#define NH 16
#define ND 256
#define NM 1024
#define BM 128           // rows per block
#define MB 64            // m-chunk
#define NCH (NM / MB)    // 16

typedef float f32x4 __attribute__((ext_vector_type(4)));
typedef float f32x16 __attribute__((ext_vector_type(16)));
typedef short bf16x8 __attribute__((ext_vector_type(8)));
typedef unsigned short u16;
typedef unsigned int u32;

__device__ __forceinline__ u16 f2bf(float f) {
  union { float f; unsigned u; } v; v.f = f;
  unsigned r = v.u + 0x7FFFu + ((v.u >> 16) & 1u);
  return (u16)(r >> 16);
}

// UpF[h]: granule byte off = mc*32768 + kh*1024 + m*16, kh in [0,32), m in [0,64)
//   elems e: up[h][kh*8+e][mc*64+m]   (up fp32 [H][256][1024])
__global__ __launch_bounds__(256) void prep_up(const float* __restrict__ src,
                                               u16* __restrict__ dst) {
  __shared__ float tile[64][65];
  const int h = blockIdx.z;
  const int m0 = blockIdx.x * 64, d0 = blockIdx.y * 64;
  const int tr = threadIdx.x >> 6, tc = threadIdx.x & 63;
  const float* s = src + (size_t)h * ND * NM;
#pragma unroll
  for (int i = 0; i < 16; ++i) {
    int r = i * 4 + tr;
    tile[r][tc] = s[(size_t)(d0 + r) * NM + m0 + tc];
  }
  __syncthreads();
  char* dh = (char*)dst + (size_t)h * NM * ND * 2;
#pragma unroll
  for (int g = 0; g < 2; ++g) {
    int gi = g * 256 + threadIdx.x;
    int kh_l = gi >> 6, m_l = gi & 63;
    bf16x8 o;
#pragma unroll
    for (int e = 0; e < 8; ++e) o[e] = (short)f2bf(tile[kh_l * 8 + e][m_l]);
    *(bf16x8*)(dh + (size_t)(m0 >> 6) * 32768 + (size_t)((d0 >> 3) + kh_l) * 1024 + m_l * 16) = o;
  }
}

// DownF[h]: granule byte off = mc*32768 + kh*4096 + d*16, kh in [0,8), d in [0,256)
//   elems e: down[h][mc*64+kh*8+e][d]   (down fp32 [H][1024][256])
__global__ __launch_bounds__(256) void prep_down(const float* __restrict__ src,
                                                 u16* __restrict__ dst) {
  __shared__ float tile[64][65];
  const int h = blockIdx.z;
  const int mc = blockIdx.x, d0 = blockIdx.y * 64;
  const int tr = threadIdx.x >> 6, tc = threadIdx.x & 63;
  const float* s = src + (size_t)h * NM * ND;
#pragma unroll
  for (int i = 0; i < 16; ++i) {
    int r = i * 4 + tr;
    tile[r][tc] = s[(size_t)(mc * 64 + r) * ND + d0 + tc];
  }
  __syncthreads();
  char* dh = (char*)dst + (size_t)h * NM * ND * 2;
#pragma unroll
  for (int g = 0; g < 2; ++g) {
    int gi = g * 256 + threadIdx.x;
    int kh_l = gi >> 6, d_l = gi & 63;
    bf16x8 o;
#pragma unroll
    for (int e = 0; e < 8; ++e) o[e] = (short)f2bf(tile[kh_l * 8 + e][d_l]);
    *(bf16x8*)(dh + (size_t)mc * 32768 + (size_t)kh_l * 4096 + (size_t)(d0 + d_l) * 16) = o;
  }
}

// xp[b][i] = bf16(x[b][perm[i]])
__global__ __launch_bounds__(1024) void permute_x(const float* __restrict__ x,
                                                  const int* __restrict__ perm,
                                                  u16* __restrict__ xp) {
  const int b = blockIdx.x;
  const int t = threadIdx.x;
  const float* xr = x + (size_t)b * 4096;
  int4 p = *(const int4*)(perm + t * 4);
  ushort4 o;
  o.x = f2bf(xr[p.x]); o.y = f2bf(xr[p.y]);
  o.z = f2bf(xr[p.z]); o.w = f2bf(xr[p.w]);
  *(ushort4*)(xp + (size_t)b * 4096 + t * 4) = o;
}

// out[b][j] = fp32(pre[b][unperm[j]]); pre is the bf16 pre-unpermute output
// that mlp_fused wrote back into the xp buffer.
__global__ __launch_bounds__(1024) void unpermute_cvt(const u16* __restrict__ pre,
                                                      const int* __restrict__ unperm,
                                                      float* __restrict__ out) {
  __shared__ u16 row[4096];
  const int b = blockIdx.x;
  const int t = threadIdx.x;
  const u16* prow = pre + (size_t)b * 4096;
  *(ushort4*)(row + t * 4) = *(const ushort4*)(prow + t * 4);
  __syncthreads();
  int4 u = *(const int4*)(unperm + t * 4);
  f32x4 v;
  union { u32 u; float f; } c0, c1, c2, c3;
  c0.u = (u32)row[u.x] << 16; c1.u = (u32)row[u.y] << 16;
  c2.u = (u32)row[u.z] << 16; c3.u = (u32)row[u.w] << 16;
  v.x = c0.f; v.y = c1.f; v.z = c2.f; v.w = c3.f;
  *(f32x4*)(out + (size_t)b * 4096 + t * 4) = v;
}

// 16-wave PRODUCER/CONSUMER MLP, spill-free at 16 waves.
// Allocation rule (pinned by R12-R17): 16 co-resident waves -> 128-reg cap
// split into arch<=64 + accum<=64 quanta. B needs accum 64 (ca), so A's ARCH
// must fit 64: R15's xr[16]=64-arch + addressing spilled ~82MB scratch.
// Fix: A-branch on 16x16x32 swapped fragments (R4/R13-verified): xr[8]=32
// arch; per-mt pa0/pa1 (8 accum) GELU'd immediately (small live range, no
// R13-style 32-read hoisting: mt-outer, 2-interleaved chain-4 inner).
// Cost: A reads 2x (1KB/16KFLOP) = +128 ds_read_b128/chunk; gain: zero
// scratch at full 16-wave TLP.
//   A-waves (w<8, s=w): 16-row strip x all 64 m (4 mt-tiles).
//   B-waves (w>=8): verbatim R15 (64r x 64d quarter, 32x32x16, ca 64).
// LDS: Us 2x32 + Ds 2x32 + Ps 2x16 = 160KB. Epilogue: bf16 pre-out -> xp.
__global__ __launch_bounds__(1024, 4) void mlp_fused(
    u16* __restrict__ xp,
    const u16* __restrict__ upF,
    const u16* __restrict__ downF) {
  __shared__ __align__(16) u16 Us[2][MB * ND];   // 2x32KB [kh32][m64][8]
  __shared__ __align__(16) u16 Ds[2][ND * MB];   // 2x32KB [kh8][d256][8]
  __shared__ __align__(16) u16 Ps[2][BM * MB];   // 2x16KB [kh8][r128][8]

  const int h   = blockIdx.y;
  const int rb  = blockIdx.x;
  const int tid = threadIdx.x;
  const int w   = tid >> 6;
  const int l   = tid & 63;
  const int lo  = l & 31;
  const int hi  = l >> 5;
  const int row0 = rb * BM;

  const char* upH = (const char*)upF + (size_t)h * NM * ND * 2;
  const char* dnH = (const char*)downF + (size_t)h * NM * ND * 2;

  // ---- prologue: all 16 waves stage Us(0) (2 insts/thread), then barrier
  {
#pragma unroll
    for (int i = 0; i < 2; ++i) {
      int t = i * 1024 + tid;
      __builtin_amdgcn_global_load_lds(
          (const __attribute__((address_space(1))) void*)(upH + (size_t)t * 16),
          (__attribute__((address_space(3))) void*)((char*)&Us[0][0] + (size_t)t * 16),
          16, 0, 0);
    }
  }
  asm volatile("s_waitcnt vmcnt(0)" ::: "memory");
  __builtin_amdgcn_s_barrier();

  if (w < 8) {
    // ================= producer (A): 16x16x32 swapped, 16-row strip ======
    const int s  = w;            // 16-row strip (8 strips = 128 rows)
    const int ll = l & 15;       // x-row within strip (frag col)
    const int q  = l >> 4;       // k-quarter (frag k = ks*32 + q*8 + e)

    // X fragments: row = row0 + s*16 + ll, k = ks*32 + q*8 + e. 32 VGPR.
    bf16x8 xr[8];
    {
      const u16* px = xp + (size_t)(row0 + s * 16 + ll) * 4096 + h * ND;
#pragma unroll
      for (int ks = 0; ks < 8; ++ks)
        xr[ks] = *(const bf16x8*)(px + ks * 32 + q * 8);
    }
    // A read base: av granule kh = ks*4+q, m = mt*16+ll ->
    //   byte = ks*4096 + (q*64 + mt*16 + ll)*16        [R13-verified]
    const size_t ubOff = ((size_t)q * 64 + ll) * 16;
    // Ps write: value (r = s*16+ll, m = mt*16 + q*4 + e) at granule
    //   (mt*2 + (q>>1))*128 + r, byte (q&1)*8           [R13-verified]
    char* const psW = (char*)&Ps[0][0] +
                      ((size_t)(q >> 1) * 128 + s * 16 + ll) * 16 + (q & 1) * 8;

    for (int i = 0; i < NCH; ++i) {
      const int c = i & 1;
      // stage Us(i+1) -> buf c^1 (A-threads: tid in [0,512), 4 insts)
      if (i + 1 < NCH) {
        const char* src = upH + (size_t)(i + 1) * 32768;
#pragma unroll
        for (int j = 0; j < 4; ++j) {
          int t = j * 512 + tid;
          __builtin_amdgcn_global_load_lds(
              (const __attribute__((address_space(1))) void*)(src + (size_t)t * 16),
              (__attribute__((address_space(3))) void*)((char*)&Us[c ^ 1][0] + (size_t)t * 16),
              16, 0, 0);
        }
      }

      // A(i): 4 mt-tiles; per mt: 8 reads + 8 MFMAs (2 indep chain-4),
      // GELU + pack immediately (accum live range = one mt iteration).
      const char* ubC = (const char*)&Us[c][0] + ubOff;
#pragma unroll
      for (int mt = 0; mt < 4; ++mt) {
        f32x4 pa0 = {0.f, 0.f, 0.f, 0.f};
        f32x4 pa1 = {0.f, 0.f, 0.f, 0.f};
        {
          const char* ub = ubC + (size_t)mt * 256;
          __builtin_amdgcn_s_setprio(1);
#pragma unroll
          for (int kk = 0; kk < 4; ++kk) {
            bf16x8 av0 = *(const bf16x8*)(ub + (size_t)(2 * kk) * 4096);
            bf16x8 av1 = *(const bf16x8*)(ub + (size_t)(2 * kk + 1) * 4096);
            pa0 = __builtin_amdgcn_mfma_f32_16x16x32_bf16(av0, xr[2 * kk], pa0, 0, 0, 0);
            pa1 = __builtin_amdgcn_mfma_f32_16x16x32_bf16(av1, xr[2 * kk + 1], pa1, 0, 0, 0);
          }
          __builtin_amdgcn_s_setprio(0);
        }
        f32x4 pa = pa0 + pa1;

        // gelu -> cvt_pk pack -> 1x ds_write_b64
        // pa[e] = P[r = s*16+ll][m = mt*16 + q*4 + e]
        float gv[4];
#pragma unroll
        for (int e = 0; e < 4; ++e) {
          float v = pa[e];
          float p = __builtin_fmaf(0.1029433f, v * v, 2.3022082f);
          float ex = __builtin_amdgcn_exp2f(v * p);
          float r = __builtin_amdgcn_rcpf(ex + 1.0f);
          gv[e] = __builtin_fmaf(-v, r, v);
        }
        u32 w0, w1;
        asm("v_cvt_pk_bf16_f32 %0, %1, %2" : "=v"(w0) : "v"(gv[0]), "v"(gv[1]));
        asm("v_cvt_pk_bf16_f32 %0, %1, %2" : "=v"(w1) : "v"(gv[2]), "v"(gv[3]));
        uint2 pk; pk.x = w0; pk.y = w1;
        *(uint2*)(psW + (size_t)c * (BM * MB * 2) + (size_t)mt * 4096) = pk;
      }

      __builtin_amdgcn_sched_barrier(0);
      asm volatile("s_waitcnt lgkmcnt(0)" ::: "memory");   // Ps published
      asm volatile("s_waitcnt vmcnt(0)" ::: "memory");     // Us(i+1) landed
      __builtin_amdgcn_s_barrier();
      __builtin_amdgcn_sched_barrier(0);
    }
    // A-waves done (pre-out written by B-waves)
  } else {
    // ================= consumer (B): verbatim R15 =================
    const int wb  = w - 8;
    const int rtp = wb & 1;   // 64-row half
    const int dq  = wb >> 1;  // 64-d quarter
    const int tb  = tid - 512;

    f32x16 ca[2][2];   // [rt2][dt] 32x32 tiles: 64r x 64d -> 64 accum
#pragma unroll
    for (int rt2 = 0; rt2 < 2; ++rt2)
#pragma unroll
      for (int dt = 0; dt < 2; ++dt)
#pragma unroll
        for (int e = 0; e < 16; ++e)
          ca[rt2][dt][e] = 0.f;

    for (int i = 0; i < NCH; ++i) {
      const int c = i & 1;
      // stage Ds(i) -> buf c (B-threads, 4 insts)
      {
        const char* src = dnH + (size_t)i * 32768;
#pragma unroll
        for (int j = 0; j < 4; ++j) {
          int t = j * 512 + tb;
          __builtin_amdgcn_global_load_lds(
              (const __attribute__((address_space(1))) void*)(src + (size_t)t * 16),
              (__attribute__((address_space(3))) void*)((char*)&Ds[c][0] + (size_t)t * 16),
              16, 0, 0);
        }
      }

      // B(i-1): C += Ps[c^1] @ Ds[c^1]
      if (i > 0) {
        const char* psb = (const char*)&Ps[c ^ 1][0];
        const char* dsb = (const char*)&Ds[c ^ 1][0];
        __builtin_amdgcn_s_setprio(1);
#pragma unroll
        for (int ks = 0; ks < 4; ++ks) {
          const size_t khp = (size_t)(ks * 2 + hi);
          bf16x8 a0 = *(const bf16x8*)(psb + khp * 2048 + (size_t)(rtp * 64 + lo) * 16);
          bf16x8 a1 = *(const bf16x8*)(psb + khp * 2048 + (size_t)(rtp * 64 + 32 + lo) * 16);
#pragma unroll
          for (int dt = 0; dt < 2; ++dt) {
            bf16x8 bv = *(const bf16x8*)(dsb + khp * 4096 + (size_t)(dq * 64 + dt * 32 + lo) * 16);
            ca[0][dt] = __builtin_amdgcn_mfma_f32_32x32x16_bf16(a0, bv, ca[0][dt], 0, 0, 0);
            ca[1][dt] = __builtin_amdgcn_mfma_f32_32x32x16_bf16(a1, bv, ca[1][dt], 0, 0, 0);
          }
        }
        __builtin_amdgcn_s_setprio(0);
      }

      __builtin_amdgcn_sched_barrier(0);
      asm volatile("s_waitcnt vmcnt(0)" ::: "memory");     // Ds(i) landed
      __builtin_amdgcn_s_barrier();
      __builtin_amdgcn_sched_barrier(0);
    }

    // final B(NCH-1): Ps[1], Ds[1]
    {
      const int c = (NCH - 1) & 1;
      const char* psb = (const char*)&Ps[c][0];
      const char* dsb = (const char*)&Ds[c][0];
      __builtin_amdgcn_s_setprio(1);
#pragma unroll
      for (int ks = 0; ks < 4; ++ks) {
        const size_t khp = (size_t)(ks * 2 + hi);
        bf16x8 a0 = *(const bf16x8*)(psb + khp * 2048 + (size_t)(rtp * 64 + lo) * 16);
        bf16x8 a1 = *(const bf16x8*)(psb + khp * 2048 + (size_t)(rtp * 64 + 32 + lo) * 16);
#pragma unroll
        for (int dt = 0; dt < 2; ++dt) {
          bf16x8 bv = *(const bf16x8*)(dsb + khp * 4096 + (size_t)(dq * 64 + dt * 32 + lo) * 16);
          ca[0][dt] = __builtin_amdgcn_mfma_f32_32x32x16_bf16(a0, bv, ca[0][dt], 0, 0, 0);
          ca[1][dt] = __builtin_amdgcn_mfma_f32_32x32x16_bf16(a1, bv, ca[1][dt], 0, 0, 0);
        }
      }
      __builtin_amdgcn_s_setprio(0);
    }

    // epilogue: bf16 pre-out into the xp buffer (coalesced u16 stores).
    // C-layout 32x32: col d = lo, row = (reg&3) + 8*(reg>>2) + 4*hi.
#pragma unroll
    for (int rt2 = 0; rt2 < 2; ++rt2)
#pragma unroll
      for (int dt = 0; dt < 2; ++dt) {
        const int d = h * ND + dq * 64 + dt * 32 + lo;
#pragma unroll
        for (int reg = 0; reg < 16; ++reg) {
          int r = rtp * 64 + rt2 * 32 + (reg & 3) + 8 * (reg >> 2) + 4 * hi;
          xp[(size_t)(row0 + r) * 4096 + d] = f2bf(ca[rt2][dt][reg]);
        }
      }
  }
}

extern "C" void kernel_launch(void* const* d_in, const int* in_sizes, int n_in,
                              void* d_out, int out_size, void* d_ws, size_t ws_size,
                              hipStream_t stream) {
  const float* x    = (const float*)d_in[0];
  const float* up   = (const float*)d_in[1];
  const float* down = (const float*)d_in[2];
  const int* perm   = (const int*)d_in[3];
  const int* unperm = (const int*)d_in[4];
  float* out = (float*)d_out;

  u16* upF   = (u16*)d_ws;                                   // 8 MB
  u16* downF = upF + (size_t)NH * NM * ND;                   // 8 MB
  u16* xp    = downF + (size_t)NH * NM * ND;                 // 128 MB (xp, then pre-out)

  // weights -> fragment-granule order (one-time, coalesced tile transposes)
  prep_up<<<dim3(NM / 64, ND / 64, NH), 256, 0, stream>>>(up, upF);
  prep_down<<<dim3(NM / 64, ND / 64, NH), 256, 0, stream>>>(down, downF);
  // xp[b][i] = bf16(x[b][perm[i]])
  permute_x<<<NB, 1024, 0, stream>>>(x, perm, xp);
  // main fused MLP: 1024 thr (8 reg-light producers + 8 consumers), 160KB.
  mlp_fused<<<dim3(NB / BM, NH), 1024, 0, stream>>>(xp, upF, downF);
  // unpermute + bf16->fp32 cvt into the real output
  unpermute_cvt<<<NB, 1024, 0, stream>>>(xp, unperm, out);
}

// Round 19
// 504.142 us; speedup vs baseline: 1.3148x; 1.0683x over previous
//
#include <hip/hip_runtime.h>
#include <hip/hip_bf16.h>
#include <math.h>

#define NB 16384
#define NH 16
#define ND 256
#define NM 1024
#define BM 128           // rows per block
#define MB 64            // m-chunk
#define NCH (NM / MB)    // 16

typedef float f32x4 __attribute__((ext_vector_type(4)));
typedef float f32x16 __attribute__((ext_vector_type(16)));
typedef short bf16x8 __attribute__((ext_vector_type(8)));
typedef unsigned short u16;
typedef unsigned int u32;

__device__ __forceinline__ u16 f2bf(float f) {
  union { float f; unsigned u; } v; v.f = f;
  unsigned r = v.u + 0x7FFFu + ((v.u >> 16) & 1u);
  return (u16)(r >> 16);
}

// UpF[h]: granule byte off = mc*32768 + kh*1024 + m*16, kh in [0,32), m in [0,64)
//   elems e: up[h][kh*8+e][mc*64+m]   (up fp32 [H][256][1024])
__global__ __launch_bounds__(256) void prep_up(const float* __restrict__ src,
                                               u16* __restrict__ dst) {
  __shared__ float tile[64][65];
  const int h = blockIdx.z;
  const int m0 = blockIdx.x * 64, d0 = blockIdx.y * 64;
  const int tr = threadIdx.x >> 6, tc = threadIdx.x & 63;
  const float* s = src + (size_t)h * ND * NM;
#pragma unroll
  for (int i = 0; i < 16; ++i) {
    int r = i * 4 + tr;
    tile[r][tc] = s[(size_t)(d0 + r) * NM + m0 + tc];
  }
  __syncthreads();
  char* dh = (char*)dst + (size_t)h * NM * ND * 2;
#pragma unroll
  for (int g = 0; g < 2; ++g) {
    int gi = g * 256 + threadIdx.x;
    int kh_l = gi >> 6, m_l = gi & 63;
    bf16x8 o;
#pragma unroll
    for (int e = 0; e < 8; ++e) o[e] = (short)f2bf(tile[kh_l * 8 + e][m_l]);
    *(bf16x8*)(dh + (size_t)(m0 >> 6) * 32768 + (size_t)((d0 >> 3) + kh_l) * 1024 + m_l * 16) = o;
  }
}

// DownF[h]: granule byte off = mc*32768 + kh*4096 + d*16, kh in [0,8), d in [0,256)
//   elems e: down[h][mc*64+kh*8+e][d]   (down fp32 [H][1024][256])
__global__ __launch_bounds__(256) void prep_down(const float* __restrict__ src,
                                                 u16* __restrict__ dst) {
  __shared__ float tile[64][65];
  const int h = blockIdx.z;
  const int mc = blockIdx.x, d0 = blockIdx.y * 64;
  const int tr = threadIdx.x >> 6, tc = threadIdx.x & 63;
  const float* s = src + (size_t)h * NM * ND;
#pragma unroll
  for (int i = 0; i < 16; ++i) {
    int r = i * 4 + tr;
    tile[r][tc] = s[(size_t)(mc * 64 + r) * ND + d0 + tc];
  }
  __syncthreads();
  char* dh = (char*)dst + (size_t)h * NM * ND * 2;
#pragma unroll
  for (int g = 0; g < 2; ++g) {
    int gi = g * 256 + threadIdx.x;
    int kh_l = gi >> 6, d_l = gi & 63;
    bf16x8 o;
#pragma unroll
    for (int e = 0; e < 8; ++e) o[e] = (short)f2bf(tile[kh_l * 8 + e][d_l]);
    *(bf16x8*)(dh + (size_t)mc * 32768 + (size_t)kh_l * 4096 + (size_t)(d0 + d_l) * 16) = o;
  }
}

// xp[b][i] = bf16(x[b][perm[i]])
__global__ __launch_bounds__(1024) void permute_x(const float* __restrict__ x,
                                                  const int* __restrict__ perm,
                                                  u16* __restrict__ xp) {
  const int b = blockIdx.x;
  const int t = threadIdx.x;
  const float* xr = x + (size_t)b * 4096;
  int4 p = *(const int4*)(perm + t * 4);
  ushort4 o;
  o.x = f2bf(xr[p.x]); o.y = f2bf(xr[p.y]);
  o.z = f2bf(xr[p.z]); o.w = f2bf(xr[p.w]);
  *(ushort4*)(xp + (size_t)b * 4096 + t * 4) = o;
}

// out[b][j] = fp32(pre[b][unperm[j]]); pre is the bf16 pre-unpermute output
// that mlp_fused wrote back into the xp buffer.
__global__ __launch_bounds__(1024) void unpermute_cvt(const u16* __restrict__ pre,
                                                      const int* __restrict__ unperm,
                                                      float* __restrict__ out) {
  __shared__ u16 row[4096];
  const int b = blockIdx.x;
  const int t = threadIdx.x;
  const u16* prow = pre + (size_t)b * 4096;
  *(ushort4*)(row + t * 4) = *(const ushort4*)(prow + t * 4);
  __syncthreads();
  int4 u = *(const int4*)(unperm + t * 4);
  f32x4 v;
  union { u32 u; float f; } c0, c1, c2, c3;
  c0.u = (u32)row[u.x] << 16; c1.u = (u32)row[u.y] << 16;
  c2.u = (u32)row[u.z] << 16; c3.u = (u32)row[u.w] << 16;
  v.x = c0.f; v.y = c1.f; v.z = c2.f; v.w = c3.f;
  *(f32x4*)(out + (size_t)b * 4096 + t * 4) = v;
}

// 16-wave PRODUCER/CONSUMER MLP: R15 structure (best: 376us, but ~67MB
// scratch spill) with HYBRID X residency to kill the spill while keeping
// 32x32 A-reads (R18 proved 16x16's 2x reads cost MORE than the spill):
//   A holds only xr[8] (K-low-half, 32 arch) resident; the K-high-half is
//   RE-LOADED from global xp each chunk in two sched_barrier-pinned groups
//   of 4 (16 transient regs). Addresses repeat every chunk -> L2-resident
//   (64KB/CU working set); loads issue a full MFMA chain before use;
//   compiler auto-vmcnt covers the wait. A arch ~60-75 -> no scratch.
//   A-waves (w<8): rtA=w&3 (32-row tile), mt=w>>2 (32-m tile); 16 reads /
//     16 MFMAs (chain-16) per chunk; GELU -> 4x b64 Ps writes.
//   B-waves (w>=8): verbatim R15 (64r x 64d quarter, ca 64 accum).
// LDS: Us 2x32 + Ds 2x32 + Ps 2x16 = 160KB. Epilogue: bf16 pre-out -> xp.
__global__ __launch_bounds__(1024, 4) void mlp_fused(
    u16* __restrict__ xp,
    const u16* __restrict__ upF,
    const u16* __restrict__ downF) {
  __shared__ __align__(16) u16 Us[2][MB * ND];   // 2x32KB [kh32][m64][8]
  __shared__ __align__(16) u16 Ds[2][ND * MB];   // 2x32KB [kh8][d256][8]
  __shared__ __align__(16) u16 Ps[2][BM * MB];   // 2x16KB [kh8][r128][8]

  const int h   = blockIdx.y;
  const int rb  = blockIdx.x;
  const int tid = threadIdx.x;
  const int w   = tid >> 6;
  const int l   = tid & 63;
  const int lo  = l & 31;
  const int hi  = l >> 5;
  const int row0 = rb * BM;

  const char* upH = (const char*)upF + (size_t)h * NM * ND * 2;
  const char* dnH = (const char*)downF + (size_t)h * NM * ND * 2;

  // ---- prologue: all 16 waves stage Us(0) (2 insts/thread), then barrier
  {
#pragma unroll
    for (int i = 0; i < 2; ++i) {
      int t = i * 1024 + tid;
      __builtin_amdgcn_global_load_lds(
          (const __attribute__((address_space(1))) void*)(upH + (size_t)t * 16),
          (__attribute__((address_space(3))) void*)((char*)&Us[0][0] + (size_t)t * 16),
          16, 0, 0);
    }
  }
  asm volatile("s_waitcnt vmcnt(0)" ::: "memory");
  __builtin_amdgcn_s_barrier();

  if (w < 8) {
    // ================= producer (A): 32x32x16, hybrid X =================
    const int rtA = w & 3;    // 32-row tile
    const int mt  = w >> 2;   // 32-m tile of the 64-m chunk

    // X row base (global): lane = x-row (rtA*32+lo); k = ks*16 + hi*8 + e.
    const char* const px =
        (const char*)(xp + (size_t)(row0 + rtA * 32 + lo) * 4096 + h * ND);
    // Resident low-half fragments: ks = 0..7. 32 VGPR.
    bf16x8 xr[8];
#pragma unroll
    for (int ks = 0; ks < 8; ++ks)
      xr[ks] = *(const bf16x8*)(px + ks * 32 + hi * 16);

    char* const psW = (char*)&Ps[0][0] + (size_t)(rtA * 32 + lo) * 16 + hi * 8;

    for (int i = 0; i < NCH; ++i) {
      const int c = i & 1;

      // high-half X group 1 (ks 8..11) -- issued before staging so the
      // compiler's auto-wait before use counts only the 4 stage loads.
      bf16x8 xv0 = *(const bf16x8*)(px + 8 * 32 + hi * 16);
      bf16x8 xv1 = *(const bf16x8*)(px + 9 * 32 + hi * 16);
      bf16x8 xv2 = *(const bf16x8*)(px + 10 * 32 + hi * 16);
      bf16x8 xv3 = *(const bf16x8*)(px + 11 * 32 + hi * 16);

      // stage Us(i+1) -> buf c^1 (A-threads: tid in [0,512), 4 insts)
      if (i + 1 < NCH) {
        const char* src = upH + (size_t)(i + 1) * 32768;
#pragma unroll
        for (int j = 0; j < 4; ++j) {
          int t = j * 512 + tid;
          __builtin_amdgcn_global_load_lds(
              (const __attribute__((address_space(1))) void*)(src + (size_t)t * 16),
              (__attribute__((address_space(3))) void*)((char*)&Us[c ^ 1][0] + (size_t)t * 16),
              16, 0, 0);
        }
      }

      // A(i): P^T[32m x 32r] = Up-frags @ X-frags, chain-16 (R15-proven)
      f32x16 pa;
#pragma unroll
      for (int e = 0; e < 16; ++e) pa[e] = 0.f;
      {
        const char* ub = (const char*)&Us[c][0] + (size_t)(mt * 32 + lo) * 16 + hi * 1024;
        __builtin_amdgcn_s_setprio(1);
#pragma unroll
        for (int ks = 0; ks < 8; ++ks) {
          bf16x8 av = *(const bf16x8*)(ub + (size_t)ks * 2048);
          pa = __builtin_amdgcn_mfma_f32_32x32x16_bf16(av, xr[ks], pa, 0, 0, 0);
        }
        // group-1 high half (compiler inserts counted vmcnt before first use)
        pa = __builtin_amdgcn_mfma_f32_32x32x16_bf16(
            *(const bf16x8*)(ub + (size_t)8 * 2048), xv0, pa, 0, 0, 0);
        pa = __builtin_amdgcn_mfma_f32_32x32x16_bf16(
            *(const bf16x8*)(ub + (size_t)9 * 2048), xv1, pa, 0, 0, 0);
        pa = __builtin_amdgcn_mfma_f32_32x32x16_bf16(
            *(const bf16x8*)(ub + (size_t)10 * 2048), xv2, pa, 0, 0, 0);
        pa = __builtin_amdgcn_mfma_f32_32x32x16_bf16(
            *(const bf16x8*)(ub + (size_t)11 * 2048), xv3, pa, 0, 0, 0);
        // group-2 loads pinned here (caps live xv at 4 -> arch fits)
        __builtin_amdgcn_sched_barrier(0);
        bf16x8 xw0 = *(const bf16x8*)(px + 12 * 32 + hi * 16);
        bf16x8 xw1 = *(const bf16x8*)(px + 13 * 32 + hi * 16);
        bf16x8 xw2 = *(const bf16x8*)(px + 14 * 32 + hi * 16);
        bf16x8 xw3 = *(const bf16x8*)(px + 15 * 32 + hi * 16);
        pa = __builtin_amdgcn_mfma_f32_32x32x16_bf16(
            *(const bf16x8*)(ub + (size_t)12 * 2048), xw0, pa, 0, 0, 0);
        pa = __builtin_amdgcn_mfma_f32_32x32x16_bf16(
            *(const bf16x8*)(ub + (size_t)13 * 2048), xw1, pa, 0, 0, 0);
        pa = __builtin_amdgcn_mfma_f32_32x32x16_bf16(
            *(const bf16x8*)(ub + (size_t)14 * 2048), xw2, pa, 0, 0, 0);
        pa = __builtin_amdgcn_mfma_f32_32x32x16_bf16(
            *(const bf16x8*)(ub + (size_t)15 * 2048), xw3, pa, 0, 0, 0);
        __builtin_amdgcn_s_setprio(0);
      }

      // gelu -> pack -> 4x ds_write_b64 into Ps[c]
      // pa[4g+e] = P[r=rtA*32+lo][m = mt*32 + g*8 + hi*4 + e]
#pragma unroll
      for (int g = 0; g < 4; ++g) {
        float gv[4];
#pragma unroll
        for (int e = 0; e < 4; ++e) {
          float v = pa[g * 4 + e];
          float p = __builtin_fmaf(0.1029433f, v * v, 2.3022082f);
          float ex = __builtin_amdgcn_exp2f(v * p);
          float r = __builtin_amdgcn_rcpf(ex + 1.0f);
          gv[e] = __builtin_fmaf(-v, r, v);
        }
        u32 w0, w1;
        asm("v_cvt_pk_bf16_f32 %0, %1, %2" : "=v"(w0) : "v"(gv[0]), "v"(gv[1]));
        asm("v_cvt_pk_bf16_f32 %0, %1, %2" : "=v"(w1) : "v"(gv[2]), "v"(gv[3]));
        uint2 pk; pk.x = w0; pk.y = w1;
        *(uint2*)(psW + (size_t)c * (BM * MB * 2) + (size_t)(mt * 4 + g) * 2048) = pk;
      }

      __builtin_amdgcn_sched_barrier(0);
      asm volatile("s_waitcnt lgkmcnt(0)" ::: "memory");   // Ps published
      asm volatile("s_waitcnt vmcnt(0)" ::: "memory");     // Us(i+1) landed
      __builtin_amdgcn_s_barrier();
      __builtin_amdgcn_sched_barrier(0);
    }
    // A-waves done (pre-out written by B-waves)
  } else {
    // ================= consumer (B): verbatim R15 =================
    const int wb  = w - 8;
    const int rtp = wb & 1;   // 64-row half
    const int dq  = wb >> 1;  // 64-d quarter
    const int tb  = tid - 512;

    f32x16 ca[2][2];   // [rt2][dt] 32x32 tiles: 64r x 64d -> 64 accum
#pragma unroll
    for (int rt2 = 0; rt2 < 2; ++rt2)
#pragma unroll
      for (int dt = 0; dt < 2; ++dt)
#pragma unroll
        for (int e = 0; e < 16; ++e)
          ca[rt2][dt][e] = 0.f;

    for (int i = 0; i < NCH; ++i) {
      const int c = i & 1;
      // stage Ds(i) -> buf c (B-threads, 4 insts)
      {
        const char* src = dnH + (size_t)i * 32768;
#pragma unroll
        for (int j = 0; j < 4; ++j) {
          int t = j * 512 + tb;
          __builtin_amdgcn_global_load_lds(
              (const __attribute__((address_space(1))) void*)(src + (size_t)t * 16),
              (__attribute__((address_space(3))) void*)((char*)&Ds[c][0] + (size_t)t * 16),
              16, 0, 0);
        }
      }

      // B(i-1): C += Ps[c^1] @ Ds[c^1]
      if (i > 0) {
        const char* psb = (const char*)&Ps[c ^ 1][0];
        const char* dsb = (const char*)&Ds[c ^ 1][0];
        __builtin_amdgcn_s_setprio(1);
#pragma unroll
        for (int ks = 0; ks < 4; ++ks) {
          const size_t khp = (size_t)(ks * 2 + hi);
          bf16x8 a0 = *(const bf16x8*)(psb + khp * 2048 + (size_t)(rtp * 64 + lo) * 16);
          bf16x8 a1 = *(const bf16x8*)(psb + khp * 2048 + (size_t)(rtp * 64 + 32 + lo) * 16);
#pragma unroll
          for (int dt = 0; dt < 2; ++dt) {
            bf16x8 bv = *(const bf16x8*)(dsb + khp * 4096 + (size_t)(dq * 64 + dt * 32 + lo) * 16);
            ca[0][dt] = __builtin_amdgcn_mfma_f32_32x32x16_bf16(a0, bv, ca[0][dt], 0, 0, 0);
            ca[1][dt] = __builtin_amdgcn_mfma_f32_32x32x16_bf16(a1, bv, ca[1][dt], 0, 0, 0);
          }
        }
        __builtin_amdgcn_s_setprio(0);
      }

      __builtin_amdgcn_sched_barrier(0);
      asm volatile("s_waitcnt vmcnt(0)" ::: "memory");     // Ds(i) landed
      __builtin_amdgcn_s_barrier();
      __builtin_amdgcn_sched_barrier(0);
    }

    // final B(NCH-1): Ps[1], Ds[1]
    {
      const int c = (NCH - 1) & 1;
      const char* psb = (const char*)&Ps[c][0];
      const char* dsb = (const char*)&Ds[c][0];
      __builtin_amdgcn_s_setprio(1);
#pragma unroll
      for (int ks = 0; ks < 4; ++ks) {
        const size_t khp = (size_t)(ks * 2 + hi);
        bf16x8 a0 = *(const bf16x8*)(psb + khp * 2048 + (size_t)(rtp * 64 + lo) * 16);
        bf16x8 a1 = *(const bf16x8*)(psb + khp * 2048 + (size_t)(rtp * 64 + 32 + lo) * 16);
#pragma unroll
        for (int dt = 0; dt < 2; ++dt) {
          bf16x8 bv = *(const bf16x8*)(dsb + khp * 4096 + (size_t)(dq * 64 + dt * 32 + lo) * 16);
          ca[0][dt] = __builtin_amdgcn_mfma_f32_32x32x16_bf16(a0, bv, ca[0][dt], 0, 0, 0);
          ca[1][dt] = __builtin_amdgcn_mfma_f32_32x32x16_bf16(a1, bv, ca[1][dt], 0, 0, 0);
        }
      }
      __builtin_amdgcn_s_setprio(0);
    }

    // epilogue: bf16 pre-out into the xp buffer (coalesced u16 stores).
    // C-layout 32x32: col d = lo, row = (reg&3) + 8*(reg>>2) + 4*hi.
#pragma unroll
    for (int rt2 = 0; rt2 < 2; ++rt2)
#pragma unroll
      for (int dt = 0; dt < 2; ++dt) {
        const int d = h * ND + dq * 64 + dt * 32 + lo;
#pragma unroll
        for (int reg = 0; reg < 16; ++reg) {
          int r = rtp * 64 + rt2 * 32 + (reg & 3) + 8 * (reg >> 2) + 4 * hi;
          xp[(size_t)(row0 + r) * 4096 + d] = f2bf(ca[rt2][dt][reg]);
        }
      }
  }
}

extern "C" void kernel_launch(void* const* d_in, const int* in_sizes, int n_in,
                              void* d_out, int out_size, void* d_ws, size_t ws_size,
                              hipStream_t stream) {
  const float* x    = (const float*)d_in[0];
  const float* up   = (const float*)d_in[1];
  const float* down = (const float*)d_in[2];
  const int* perm   = (const int*)d_in[3];
  const int* unperm = (const int*)d_in[4];
  float* out = (float*)d_out;

  u16* upF   = (u16*)d_ws;                                   // 8 MB
  u16* downF = upF + (size_t)NH * NM * ND;                   // 8 MB
  u16* xp    = downF + (size_t)NH * NM * ND;                 // 128 MB (xp, then pre-out)

  // weights -> fragment-granule order (one-time, coalesced tile transposes)
  prep_up<<<dim3(NM / 64, ND / 64, NH), 256, 0, stream>>>(up, upF);
  prep_down<<<dim3(NM / 64, ND / 64, NH), 256, 0, stream>>>(down, downF);
  // xp[b][i] = bf16(x[b][perm[i]])
  permute_x<<<NB, 1024, 0, stream>>>(x, perm, xp);
  // main fused MLP: 1024 thr (8 hybrid-X producers + 8 consumers), 160KB.
  mlp_fused<<<dim3(NB / BM, NH), 1024, 0, stream>>>(xp, upF, downF);
  // unpermute + bf16->fp32 cvt into the real output
  unpermute_cvt<<<NB, 1024, 0, stream>>>(xp, unperm, out);
}